// Round 21
// baseline (315.536 us; speedup 1.0000x reference)
//
#include <hip/hip_runtime.h>
#include <hip/hip_bf16.h>
#include <hip/hip_cooperative_groups.h>
#include <math.h>

namespace cg = cooperative_groups;

#define N_NODES 50000
#define N_EDGES 800000
#define IN_F 128
#define OUT_F 64
#define NEG_SLOPE 0.2f

#define GRID 256
#define TPB 1024
#define GEMM_BLKS 98        // 98 blocks x 16 waves = 1568 waves x 2 tiles x 16 rows >= 50000
#define TPW 2               // row-tiles per wave
#define BIN_BLKS 156        // binning blocks; 156 x 5152 >= 800000
#define BCHUNK 5152
#define PSZ 128             // nodes per partition
#define NPART ((N_NODES + PSZ - 1) / PSZ)   // 391
#define PADCAP 3072         // per-partition edge-list cap (mean 2048, +22 sigma)
#define CAP 64              // per-node slot cap (self-loop + max deg ~44)

typedef __attribute__((ext_vector_type(8))) short bf16x8;
typedef __attribute__((ext_vector_type(4))) float f32x4;

__device__ __forceinline__ short f2bf_s(float f) {
    return (short)__builtin_bit_cast(unsigned short, __float2bfloat16(f));
}
__device__ __forceinline__ unsigned short f2bf_u(float f) {
    return __builtin_bit_cast(unsigned short, __float2bfloat16(f));
}
__device__ __forceinline__ float bf_lo(unsigned u) { return __uint_as_float(u << 16); }
__device__ __forceinline__ float bf_hi(unsigned u) { return __uint_as_float(u & 0xFFFF0000u); }

// One cooperative kernel: phase0 (prep) -> sync -> phaseA (GEMM || binning)
// -> sync -> phaseB (LDS-CSR build + node softmax/aggregate).
__global__ __launch_bounds__(TPB) void k_all(
    const float* __restrict__ x, const float* __restrict__ W,
    const float* __restrict__ att_src, const float* __restrict__ att_dst,
    const int* __restrict__ ei, const float* __restrict__ bias,
    unsigned short* __restrict__ h, float* __restrict__ a_src,
    float* __restrict__ a_dst, int* __restrict__ gcnt,
    unsigned* __restrict__ glist, unsigned short* __restrict__ wa_g,
    unsigned short* __restrict__ wd_g, float* __restrict__ out) {
    cg::grid_group grid = cg::this_grid();
    __shared__ int bcnt[NPART];
    __shared__ int bbase[NPART];
    __shared__ unsigned short lcsr[PSZ][CAP];  // 16 KB
    __shared__ int lcnt[PSZ];

    int bid = blockIdx.x;
    int tid = threadIdx.x;

    // ---------------- phase 0: prep ----------------
    if (bid == 0 && tid < IN_F) {
        float s1 = 0.f, s2 = 0.f;
        const float4* wr = reinterpret_cast<const float4*>(&W[tid * OUT_F]);
        const float4* as = reinterpret_cast<const float4*>(att_src);
        const float4* ad = reinterpret_cast<const float4*>(att_dst);
#pragma unroll
        for (int c4 = 0; c4 < OUT_F / 4; ++c4) {
            float4 wv = wr[c4];
            float4 a1 = as[c4];
            float4 a2 = ad[c4];
            s1 = fmaf(wv.x, a1.x, s1); s2 = fmaf(wv.x, a2.x, s2);
            s1 = fmaf(wv.y, a1.y, s1); s2 = fmaf(wv.y, a2.y, s2);
            s1 = fmaf(wv.z, a1.z, s1); s2 = fmaf(wv.z, a2.z, s2);
            s1 = fmaf(wv.w, a1.w, s1); s2 = fmaf(wv.w, a2.w, s2);
        }
        wa_g[tid] = f2bf_u(s1);
        wd_g[tid] = f2bf_u(s2);
    }
    if (bid == 1) {
        for (int i = tid; i < NPART; i += TPB) gcnt[i] = 0;
    }
    __threadfence();
    grid.sync();

    // ---------------- phase A ----------------
    if (bid < GEMM_BLKS) {
        // GEMM: wave g handles TPW row-tiles; W fragments reloaded per ks from
        // L1-hot W (keeps VGPR < 128 for the 1024-thread co-residency cap).
        int w = tid >> 6;
        int lane = tid & 63;
        int col = lane & 15;   // B/D column group (m89-verified layout)
        int kg = lane >> 4;    // k-group of 8
        int g = bid * 16 + w;

        // bf5: col 0 = wa, col 1 = wd, other cols zero (cached, 16 regs)
        bf16x8 bf5[4];
#pragma unroll
        for (int ks = 0; ks < 4; ++ks) {
            bf16x8 b = {0, 0, 0, 0, 0, 0, 0, 0};
            if (col == 0) b = *reinterpret_cast<const bf16x8*>(&wa_g[ks * 32 + kg * 8]);
            if (col == 1) b = *reinterpret_cast<const bf16x8*>(&wd_g[ks * 32 + kg * 8]);
            bf5[ks] = b;
        }

        for (int it = 0; it < TPW; ++it) {
            int r0 = (g * TPW + it) * 16;
            if (r0 >= N_NODES) break;
            const float* xp = &x[(size_t)(r0 + col) * IN_F + kg * 8];

            bf16x8 af[4];
#pragma unroll
            for (int ks = 0; ks < 4; ++ks) {
                float4 xa = *reinterpret_cast<const float4*>(xp + ks * 32);
                float4 xb = *reinterpret_cast<const float4*>(xp + ks * 32 + 4);
                bf16x8 a;
                a[0] = f2bf_s(xa.x); a[1] = f2bf_s(xa.y);
                a[2] = f2bf_s(xa.z); a[3] = f2bf_s(xa.w);
                a[4] = f2bf_s(xb.x); a[5] = f2bf_s(xb.y);
                a[6] = f2bf_s(xb.z); a[7] = f2bf_s(xb.w);
                af[ks] = a;
            }

            f32x4 acc[4], acc5;
            f32x4 z = {0.f, 0.f, 0.f, 0.f};
#pragma unroll
            for (int nt = 0; nt < 4; ++nt) acc[nt] = z;
            acc5 = z;
#pragma unroll
            for (int ks = 0; ks < 4; ++ks) {
                bf16x8 b0, b1, b2, b3;
#pragma unroll
                for (int i = 0; i < 8; ++i) {
                    const float4 w4 = *reinterpret_cast<const float4*>(
                        &W[(ks * 32 + kg * 8 + i) * OUT_F + col * 4]);
                    b0[i] = f2bf_s(w4.x); b1[i] = f2bf_s(w4.y);
                    b2[i] = f2bf_s(w4.z); b3[i] = f2bf_s(w4.w);
                }
                acc[0] = __builtin_amdgcn_mfma_f32_16x16x32_bf16(af[ks], b0, acc[0], 0, 0, 0);
                acc[1] = __builtin_amdgcn_mfma_f32_16x16x32_bf16(af[ks], b1, acc[1], 0, 0, 0);
                acc[2] = __builtin_amdgcn_mfma_f32_16x16x32_bf16(af[ks], b2, acc[2], 0, 0, 0);
                acc[3] = __builtin_amdgcn_mfma_f32_16x16x32_bf16(af[ks], b3, acc[3], 0, 0, 0);
                acc5 = __builtin_amdgcn_mfma_f32_16x16x32_bf16(af[ks], bf5[ks], acc5, 0, 0, 0);
            }

#pragma unroll
            for (int j = 0; j < 4; ++j) {
                int r = r0 + kg * 4 + j;
                ushort4 hv;
                hv.x = f2bf_u(acc[0][j]);
                hv.y = f2bf_u(acc[1][j]);
                hv.z = f2bf_u(acc[2][j]);
                hv.w = f2bf_u(acc[3][j]);
                *reinterpret_cast<ushort4*>(&h[(size_t)r * OUT_F + col * 4]) = hv;
            }
            if (col < 2) {
                float* ap = (col == 0) ? a_src : a_dst;
#pragma unroll
                for (int j = 0; j < 4; ++j) ap[r0 + kg * 4 + j] = acc5[j];
            }
        }
    } else if (bid < GEMM_BLKS + BIN_BLKS) {
        // binning: 5152-edge chunk, 6 coalesced strided passes
        int c = bid - GEMM_BLKS;
        int base = c * BCHUNK;
        for (int i = tid; i < NPART; i += TPB) bcnt[i] = 0;
        __syncthreads();

        int sv[6], dv[6], sl[6];
        bool vv[6];
#pragma unroll
        for (int j = 0; j < 6; ++j) {
            int o = j * TPB + tid;
            int e = base + o;
            vv[j] = (o < BCHUNK) && (e < N_EDGES);
            if (vv[j]) {
                sv[j] = ei[e];
                dv[j] = ei[N_EDGES + e];
                sl[j] = atomicAdd(&bcnt[dv[j] >> 7], 1);  // LDS atomic
            }
        }
        __syncthreads();
        for (int i = tid; i < NPART; i += TPB)
            bbase[i] = bcnt[i] ? atomicAdd(&gcnt[i], bcnt[i]) : 0;
        __syncthreads();
#pragma unroll
        for (int j = 0; j < 6; ++j) {
            if (vv[j]) {
                int p = dv[j] >> 7;
                int idx = bbase[p] + sl[j];
                if (idx < PADCAP)
                    glist[(size_t)p * PADCAP + idx] =
                        (unsigned)(sv[j] & 0xFFFF) | ((unsigned)(dv[j] & (PSZ - 1)) << 16);
            }
        }
    }
    __threadfence();
    grid.sync();

    // ---------------- phase B: CSR build + node aggregate ----------------
    int w = tid >> 6;
    int lane = tid & 63;
    int half = lane >> 5;
    int hl = lane & 31;
    int es = hl >> 3;     // edge slot within trip (0..3)
    int cb = hl & 7;      // channel block (8 channels)
    int hbase = half << 5;

    for (int p = bid; p < NPART; p += GRID) {
        int n0 = p * PSZ;
        for (int i = tid; i < PSZ; i += TPB) {
            lcnt[i] = 1;                              // slot 0 = self-loop
            lcsr[i][0] = (unsigned short)(n0 + i);
        }
        __syncthreads();

        int m = min(gcnt[p], PADCAP);
        size_t base = (size_t)p * PADCAP;
        for (int i = tid; i < m; i += TPB) {
            unsigned u = glist[base + i];
            int dl = u >> 16;
            int k = atomicAdd(&lcnt[dl], 1);
            if (k < CAP) lcsr[dl][k] = (unsigned short)(u & 0xFFFFu);
        }
        __syncthreads();

        int nn_nodes = min(PSZ, N_NODES - n0);
        for (int it = 0; it < PSZ / 32; ++it) {
            int nl = it * 32 + w * 2 + half;
            if (nl < nn_nodes) {
                int node = n0 + nl;
                int n = min(lcnt[nl], CAP);
                float a_d = a_dst[node];
                float acc8[8];
#pragma unroll
                for (int i = 0; i < 8; ++i) acc8[i] = 0.f;
                float l = 0.f;

                if (n <= 32) {
                    int s = 0;
                    float pp = 0.f;
                    if (hl < n) {
                        s = lcsr[nl][hl];
                        float t = a_src[s] + a_d;
                        t = (t > 0.f) ? t : NEG_SLOPE * t;
                        pp = __expf(t);
                    }
                    l = pp;
                    for (int off = 16; off; off >>= 1) l += __shfl_xor(l, off, 64);

                    int jn = (n + 3) >> 2;
                    for (int j = 0; j < jn; ++j) {
                        int sl2 = j * 4 + es;
                        float pj = __shfl(pp, hbase + sl2, 64);
                        int sj = __shfl(s, hbase + sl2, 64);
                        if (sl2 < n) {
                            uint4 hv = *reinterpret_cast<const uint4*>(
                                &h[(size_t)sj * OUT_F + cb * 8]);
                            acc8[0] = fmaf(pj, bf_lo(hv.x), acc8[0]);
                            acc8[1] = fmaf(pj, bf_hi(hv.x), acc8[1]);
                            acc8[2] = fmaf(pj, bf_lo(hv.y), acc8[2]);
                            acc8[3] = fmaf(pj, bf_hi(hv.y), acc8[3]);
                            acc8[4] = fmaf(pj, bf_lo(hv.z), acc8[4]);
                            acc8[5] = fmaf(pj, bf_hi(hv.z), acc8[5]);
                            acc8[6] = fmaf(pj, bf_lo(hv.w), acc8[6]);
                            acc8[7] = fmaf(pj, bf_hi(hv.w), acc8[7]);
                        }
                    }
                } else {
                    for (int b2 = 0; b2 < n; b2 += 32) {
                        int nn = min(32, n - b2);
                        int s = 0;
                        float pp = 0.f;
                        if (hl < nn) {
                            s = lcsr[nl][b2 + hl];
                            float t = a_src[s] + a_d;
                            t = (t > 0.f) ? t : NEG_SLOPE * t;
                            pp = __expf(t);
                        }
                        float ps = pp;
                        for (int off = 16; off; off >>= 1) ps += __shfl_xor(ps, off, 64);
                        l += ps;

                        int jn = (nn + 3) >> 2;
                        for (int j = 0; j < jn; ++j) {
                            int sl2 = j * 4 + es;
                            float pj = __shfl(pp, hbase + sl2, 64);
                            int sj = __shfl(s, hbase + sl2, 64);
                            if (sl2 < nn) {
                                uint4 hv = *reinterpret_cast<const uint4*>(
                                    &h[(size_t)sj * OUT_F + cb * 8]);
                                acc8[0] = fmaf(pj, bf_lo(hv.x), acc8[0]);
                                acc8[1] = fmaf(pj, bf_hi(hv.x), acc8[1]);
                                acc8[2] = fmaf(pj, bf_lo(hv.y), acc8[2]);
                                acc8[3] = fmaf(pj, bf_hi(hv.y), acc8[3]);
                                acc8[4] = fmaf(pj, bf_lo(hv.z), acc8[4]);
                                acc8[5] = fmaf(pj, bf_hi(hv.z), acc8[5]);
                                acc8[6] = fmaf(pj, bf_lo(hv.w), acc8[6]);
                                acc8[7] = fmaf(pj, bf_hi(hv.w), acc8[7]);
                            }
                        }
                    }
                }

#pragma unroll
                for (int i = 0; i < 8; ++i) {
                    acc8[i] += __shfl_xor(acc8[i], 8, 64);
                    acc8[i] += __shfl_xor(acc8[i], 16, 64);
                }

                if (hl < 8) {
                    float inv = 1.f / (l + 1e-16f);
                    const float4 b0 = *reinterpret_cast<const float4*>(&bias[cb * 8]);
                    const float4 b1 = *reinterpret_cast<const float4*>(&bias[cb * 8 + 4]);
                    float4 o0, o1;
                    o0.x = fmaxf(acc8[0] * inv + b0.x, 0.f);
                    o0.y = fmaxf(acc8[1] * inv + b0.y, 0.f);
                    o0.z = fmaxf(acc8[2] * inv + b0.z, 0.f);
                    o0.w = fmaxf(acc8[3] * inv + b0.w, 0.f);
                    o1.x = fmaxf(acc8[4] * inv + b1.x, 0.f);
                    o1.y = fmaxf(acc8[5] * inv + b1.y, 0.f);
                    o1.z = fmaxf(acc8[6] * inv + b1.z, 0.f);
                    o1.w = fmaxf(acc8[7] * inv + b1.w, 0.f);
                    float* op = &out[(size_t)node * OUT_F + cb * 8];
                    *reinterpret_cast<float4*>(op) = o0;
                    *reinterpret_cast<float4*>(op + 4) = o1;
                }
            }
        }
        __syncthreads();  // lcsr/lcnt reused next partition
    }
}

extern "C" void kernel_launch(void* const* d_in, const int* in_sizes, int n_in,
                              void* d_out, int out_size, void* d_ws, size_t ws_size,
                              hipStream_t stream) {
    const float* x       = (const float*)d_in[0];
    const int*   ei      = (const int*)d_in[1];
    const float* W       = (const float*)d_in[2];
    const float* att_src = (const float*)d_in[3];
    const float* att_dst = (const float*)d_in[4];
    const float* bias    = (const float*)d_in[5];
    float* out = (float*)d_out;

    char* wsp = (char*)d_ws;
    unsigned short* h = (unsigned short*)wsp;
    wsp += (size_t)N_NODES * OUT_F * sizeof(unsigned short);
    float* a_src = (float*)wsp; wsp += (size_t)N_NODES * sizeof(float);
    float* a_dst = (float*)wsp; wsp += (size_t)N_NODES * sizeof(float);
    int*   gcnt  = (int*)wsp;   wsp += (size_t)NPART * sizeof(int);
    wsp = (char*)(((size_t)wsp + 15) & ~(size_t)15);
    unsigned short* wa = (unsigned short*)wsp; wsp += IN_F * sizeof(unsigned short);
    unsigned short* wd = (unsigned short*)wsp; wsp += IN_F * sizeof(unsigned short);
    wsp = (char*)(((size_t)wsp + 15) & ~(size_t)15);
    unsigned* glist = (unsigned*)wsp;
    wsp += (size_t)NPART * PADCAP * sizeof(unsigned);

    void* kargs[] = {
        (void*)&x, (void*)&W, (void*)&att_src, (void*)&att_dst, (void*)&ei,
        (void*)&bias, (void*)&h, (void*)&a_src, (void*)&a_dst, (void*)&gcnt,
        (void*)&glist, (void*)&wa, (void*)&wd, (void*)&out,
    };
    hipLaunchCooperativeKernel((const void*)k_all, dim3(GRID), dim3(TPB),
                               kargs, 0, stream);
}

// Round 22
// 48.674 us; speedup vs baseline: 6.4827x; 6.4827x over previous
//
#include <hip/hip_runtime.h>
#include <hip/hip_bf16.h>
#include <math.h>

#define N_NODES 50000
#define N_EDGES 800000
#define IN_F 128
#define OUT_F 64
#define NEG_SLOPE 0.2f

#define CAP 64              // per-node slot capacity (self-loop + max deg ~44)
#define GB 196              // gemm blocks: 784 waves x 4 row-tiles x 16 rows >= 50000
#define TPW 4               // row-tiles per wave
#define PSZ 128             // nodes per partition
#define NPART ((N_NODES + PSZ - 1) / PSZ)   // 391
#define PADCAP 3072         // edge-list cap per partition (mean 2048, sigma 45 -> +22s)
#define CHUNK 2048          // edges per fill block (256 thr x 8)
#define NCHUNK ((N_EDGES + CHUNK - 1) / CHUNK)  // 391

typedef __attribute__((ext_vector_type(8))) short bf16x8;
typedef __attribute__((ext_vector_type(4))) float f32x4;

// fp32 -> bf16 RNE via native conversion (compiler fuses pairs to v_cvt_pk_bf16_f32)
__device__ __forceinline__ short f2bf_s(float f) {
    return (short)__builtin_bit_cast(unsigned short, __float2bfloat16(f));
}
__device__ __forceinline__ unsigned short f2bf_u(float f) {
    return __builtin_bit_cast(unsigned short, __float2bfloat16(f));
}
__device__ __forceinline__ float bf_lo(unsigned u) { return __uint_as_float(u << 16); }
__device__ __forceinline__ float bf_hi(unsigned u) { return __uint_as_float(u & 0xFFFF0000u); }

// Prep: wa = W@att_src, wd = W@att_dst (bf16), and zero gcnt (replaces memset).
// float4 row walk (same fmaf order as scalar -> bit-identical result).
__global__ __launch_bounds__(256) void k_prep(
    const float* __restrict__ W, const float* __restrict__ att_src,
    const float* __restrict__ att_dst, unsigned short* __restrict__ wa,
    unsigned short* __restrict__ wd, int* __restrict__ gcnt) {
    int t = threadIdx.x;
    for (int i = t; i < NPART; i += 256) gcnt[i] = 0;
    if (t < IN_F) {
        float s1 = 0.f, s2 = 0.f;
        const float4* wr = reinterpret_cast<const float4*>(&W[t * OUT_F]);
        const float4* as = reinterpret_cast<const float4*>(att_src);
        const float4* ad = reinterpret_cast<const float4*>(att_dst);
#pragma unroll
        for (int c4 = 0; c4 < OUT_F / 4; ++c4) {
            float4 wv = wr[c4];
            float4 a1 = as[c4];
            float4 a2 = ad[c4];
            s1 = fmaf(wv.x, a1.x, s1); s2 = fmaf(wv.x, a2.x, s2);
            s1 = fmaf(wv.y, a1.y, s1); s2 = fmaf(wv.y, a2.y, s2);
            s1 = fmaf(wv.z, a1.z, s1); s2 = fmaf(wv.z, a2.z, s2);
            s1 = fmaf(wv.w, a1.w, s1); s2 = fmaf(wv.w, a2.w, s2);
        }
        wa[t] = f2bf_u(s1);
        wd[t] = f2bf_u(s2);
    }
}

// Fused: blocks [0,GB) = MFMA h=x@W (+ 5th MFMA producing a_src/a_dst directly,
// no shuffle epilogue); blocks [GB,GB+NCHUNK) = phase-1 edge binning.
__global__ __launch_bounds__(256) void k_fused(
    const float* __restrict__ x, const float* __restrict__ W,
    const unsigned short* __restrict__ wa, const unsigned short* __restrict__ wd,
    const int* __restrict__ ei, unsigned short* __restrict__ h,
    float* __restrict__ a_src, float* __restrict__ a_dst,
    int* __restrict__ gcnt, unsigned* __restrict__ glist) {
    int tid = threadIdx.x;

    if (blockIdx.x >= GB) {
        // ---- phase-1 binning: this block owns edge chunk [e0, e0+2048) ----
        __shared__ int bcnt[NPART];
        __shared__ int bbase[NPART];
        int f = blockIdx.x - GB;
        for (int i = tid; i < NPART; i += 256) bcnt[i] = 0;
        __syncthreads();

        int e0 = f * CHUNK + tid * 8;
        bool val = e0 < N_EDGES;  // N_EDGES % 8 == 0: 8 edges all-valid
        int sv[8], dv[8], sl[8];
        if (val) {
            const int4 sa = *reinterpret_cast<const int4*>(ei + e0);
            const int4 sb = *reinterpret_cast<const int4*>(ei + e0 + 4);
            const int4 da = *reinterpret_cast<const int4*>(ei + N_EDGES + e0);
            const int4 db = *reinterpret_cast<const int4*>(ei + N_EDGES + e0 + 4);
            sv[0]=sa.x; sv[1]=sa.y; sv[2]=sa.z; sv[3]=sa.w;
            sv[4]=sb.x; sv[5]=sb.y; sv[6]=sb.z; sv[7]=sb.w;
            dv[0]=da.x; dv[1]=da.y; dv[2]=da.z; dv[3]=da.w;
            dv[4]=db.x; dv[5]=db.y; dv[6]=db.z; dv[7]=db.w;
#pragma unroll
            for (int i = 0; i < 8; ++i)
                sl[i] = atomicAdd(&bcnt[dv[i] >> 7], 1);   // LDS atomic
        }
        __syncthreads();
        for (int i = tid; i < NPART; i += 256)
            bbase[i] = bcnt[i] ? atomicAdd(&gcnt[i], bcnt[i]) : 0;
        __syncthreads();
        if (val) {
#pragma unroll
            for (int i = 0; i < 8; ++i) {
                int p = dv[i] >> 7;
                int idx = bbase[p] + sl[i];
                if (idx < PADCAP)
                    glist[(size_t)p * PADCAP + idx] =
                        (unsigned)(sv[i] & 0xFFFF) | ((unsigned)(dv[i] & (PSZ - 1)) << 16);
            }
        }
        return;
    }

    // ---- MFMA gemm path: wave gw handles row-tiles gw*4 .. gw*4+3 (16 rows each)
    // 50000 % 16 == 0 -> every active tile is full; no row guards needed.
    int w = tid >> 6;
    int lane = tid & 63;
    int col = lane & 15;   // A: row-within-tile; B/D: column (m89-verified layout)
    int kg = lane >> 4;    // k-group of 8
    int gw = blockIdx.x * 4 + w;

    // B fragments via float4 loads: MFMA #nt's column col = channel col*4+nt
    // (lane's 4 outputs per row are consecutive channels -> packed ushort4 store).
    bf16x8 bf[4][4];
#pragma unroll
    for (int ks = 0; ks < 4; ++ks) {
        bf16x8 b0, b1, b2, b3;
#pragma unroll
        for (int i = 0; i < 8; ++i) {
            const float4 w4 = *reinterpret_cast<const float4*>(
                &W[(ks * 32 + kg * 8 + i) * OUT_F + col * 4]);
            b0[i] = f2bf_s(w4.x); b1[i] = f2bf_s(w4.y);
            b2[i] = f2bf_s(w4.z); b3[i] = f2bf_s(w4.w);
        }
        bf[ks][0] = b0; bf[ks][1] = b1; bf[ks][2] = b2; bf[ks][3] = b3;
    }
    // 5th-MFMA B fragment: col 0 = wa, col 1 = wd, other cols zero.
    bf16x8 bf5[4];
#pragma unroll
    for (int ks = 0; ks < 4; ++ks) {
        bf16x8 b = {0, 0, 0, 0, 0, 0, 0, 0};
        if (col == 0) b = *reinterpret_cast<const bf16x8*>(&wa[ks * 32 + kg * 8]);
        if (col == 1) b = *reinterpret_cast<const bf16x8*>(&wd[ks * 32 + kg * 8]);
        bf5[ks] = b;
    }

    for (int it = 0; it < TPW; ++it) {
        int r0 = (gw * TPW + it) * 16;
        if (r0 >= N_NODES) break;
        const float* xp = &x[(size_t)(r0 + col) * IN_F + kg * 8];

        bf16x8 af[4];
#pragma unroll
        for (int ks = 0; ks < 4; ++ks) {
            float4 xa = *reinterpret_cast<const float4*>(xp + ks * 32);
            float4 xb = *reinterpret_cast<const float4*>(xp + ks * 32 + 4);
            bf16x8 a;
            a[0] = f2bf_s(xa.x); a[1] = f2bf_s(xa.y);
            a[2] = f2bf_s(xa.z); a[3] = f2bf_s(xa.w);
            a[4] = f2bf_s(xb.x); a[5] = f2bf_s(xb.y);
            a[6] = f2bf_s(xb.z); a[7] = f2bf_s(xb.w);
            af[ks] = a;
        }

        f32x4 acc[4], acc5;
        f32x4 z = {0.f, 0.f, 0.f, 0.f};
#pragma unroll
        for (int nt = 0; nt < 4; ++nt) acc[nt] = z;
        acc5 = z;
#pragma unroll
        for (int ks = 0; ks < 4; ++ks) {
#pragma unroll
            for (int nt = 0; nt < 4; ++nt)
                acc[nt] = __builtin_amdgcn_mfma_f32_16x16x32_bf16(
                    af[ks], bf[ks][nt], acc[nt], 0, 0, 0);
            acc5 = __builtin_amdgcn_mfma_f32_16x16x32_bf16(
                af[ks], bf5[ks], acc5, 0, 0, 0);
        }

        // epilogue: D row = kg*4+j, lane owns channels col*4..col*4+3
#pragma unroll
        for (int j = 0; j < 4; ++j) {
            int r = r0 + kg * 4 + j;
            ushort4 hv;
            hv.x = f2bf_u(acc[0][j]);
            hv.y = f2bf_u(acc[1][j]);
            hv.z = f2bf_u(acc[2][j]);
            hv.w = f2bf_u(acc[3][j]);
            *reinterpret_cast<ushort4*>(&h[(size_t)r * OUT_F + col * 4]) = hv;
        }
        if (col < 2) {
            float* ap = (col == 0) ? a_src : a_dst;
#pragma unroll
            for (int j = 0; j < 4; ++j) ap[r0 + kg * 4 + j] = acc5[j];
        }
    }
}

// Fused CSR-build + node aggregation: one 1024-thread block per partition.
// Build the partition's CSR slice in LDS (self-loop pre-seeded at slot 0),
// then 16 waves x 2 halves process the 128 nodes. Gather: 4 edges per trip
// per half (8 lanes x uint4 = 8 channels per lane). No global csr.
__global__ __launch_bounds__(1024) void k_csr_node(
    const int* __restrict__ gcnt, const unsigned* __restrict__ glist,
    const float* __restrict__ a_src, const float* __restrict__ a_dst,
    const unsigned short* __restrict__ h, const float* __restrict__ bias,
    float* __restrict__ out) {
    __shared__ unsigned short lcsr[PSZ][CAP];  // 16 KB
    __shared__ int lcnt[PSZ];
    int p = blockIdx.x;
    int tid = threadIdx.x;
    int n0 = p * PSZ;

    for (int i = tid; i < PSZ; i += 1024) {
        lcnt[i] = 1;                              // slot 0 = self-loop
        lcsr[i][0] = (unsigned short)(n0 + i);
    }
    __syncthreads();

    int m = min(gcnt[p], PADCAP);
    size_t base = (size_t)p * PADCAP;
    for (int i = tid; i < m; i += 1024) {
        unsigned u = glist[base + i];
        int dl = u >> 16;
        int k = atomicAdd(&lcnt[dl], 1);
        if (k < CAP) lcsr[dl][k] = (unsigned short)(u & 0xFFFFu);
    }
    __syncthreads();

    int w = tid >> 6;
    int lane = tid & 63;
    int half = lane >> 5;
    int hl = lane & 31;
    int es = hl >> 3;     // edge slot within trip (0..3)
    int cb = hl & 7;      // channel block (8 channels: cb*8 .. cb*8+7)
    int hbase = half << 5;
    int nn_nodes = min(PSZ, N_NODES - n0);

    for (int it = 0; it < PSZ / 32; ++it) {
        int nl = it * 32 + w * 2 + half;
        if (nl >= nn_nodes) continue;
        int node = n0 + nl;
        int n = min(lcnt[nl], CAP);
        float a_d = a_dst[node];
        float acc8[8];
#pragma unroll
        for (int i = 0; i < 8; ++i) acc8[i] = 0.f;
        float l = 0.f;

        if (n <= 32) {
            int s = 0;
            float pp = 0.f;
            if (hl < n) {
                s = lcsr[nl][hl];
                float t = a_src[s] + a_d;
                t = (t > 0.f) ? t : NEG_SLOPE * t;
                pp = __expf(t);
            }
            l = pp;
            for (int off = 16; off; off >>= 1) l += __shfl_xor(l, off, 64);

            int jn = (n + 3) >> 2;
            for (int j = 0; j < jn; ++j) {
                int sl = j * 4 + es;
                float pj = __shfl(pp, hbase + sl, 64);
                int sj = __shfl(s, hbase + sl, 64);
                if (sl < n) {
                    uint4 hv =
                        *reinterpret_cast<const uint4*>(&h[(size_t)sj * OUT_F + cb * 8]);
                    acc8[0] = fmaf(pj, bf_lo(hv.x), acc8[0]);
                    acc8[1] = fmaf(pj, bf_hi(hv.x), acc8[1]);
                    acc8[2] = fmaf(pj, bf_lo(hv.y), acc8[2]);
                    acc8[3] = fmaf(pj, bf_hi(hv.y), acc8[3]);
                    acc8[4] = fmaf(pj, bf_lo(hv.z), acc8[4]);
                    acc8[5] = fmaf(pj, bf_hi(hv.z), acc8[5]);
                    acc8[6] = fmaf(pj, bf_lo(hv.w), acc8[6]);
                    acc8[7] = fmaf(pj, bf_hi(hv.w), acc8[7]);
                }
            }
        } else {
            // general path (rare): 32-wide chunks over [0, n)
            for (int b2 = 0; b2 < n; b2 += 32) {
                int nn = min(32, n - b2);
                int s = 0;
                float pp = 0.f;
                if (hl < nn) {
                    s = lcsr[nl][b2 + hl];
                    float t = a_src[s] + a_d;
                    t = (t > 0.f) ? t : NEG_SLOPE * t;
                    pp = __expf(t);
                }
                float ps = pp;
                for (int off = 16; off; off >>= 1) ps += __shfl_xor(ps, off, 64);
                l += ps;

                int jn = (nn + 3) >> 2;
                for (int j = 0; j < jn; ++j) {
                    int sl = j * 4 + es;
                    float pj = __shfl(pp, hbase + sl, 64);
                    int sj = __shfl(s, hbase + sl, 64);
                    if (sl < nn) {
                        uint4 hv = *reinterpret_cast<const uint4*>(
                            &h[(size_t)sj * OUT_F + cb * 8]);
                        acc8[0] = fmaf(pj, bf_lo(hv.x), acc8[0]);
                        acc8[1] = fmaf(pj, bf_hi(hv.x), acc8[1]);
                        acc8[2] = fmaf(pj, bf_lo(hv.y), acc8[2]);
                        acc8[3] = fmaf(pj, bf_hi(hv.y), acc8[3]);
                        acc8[4] = fmaf(pj, bf_lo(hv.z), acc8[4]);
                        acc8[5] = fmaf(pj, bf_hi(hv.z), acc8[5]);
                        acc8[6] = fmaf(pj, bf_lo(hv.w), acc8[6]);
                        acc8[7] = fmaf(pj, bf_hi(hv.w), acc8[7]);
                    }
                }
            }
        }

        // combine the 4 edge-slot groups within each half (lane bits 3,4)
#pragma unroll
        for (int i = 0; i < 8; ++i) {
            acc8[i] += __shfl_xor(acc8[i], 8, 64);
            acc8[i] += __shfl_xor(acc8[i], 16, 64);
        }

        if (hl < 8) {
            float inv = 1.f / (l + 1e-16f);
            const float4 b0 = *reinterpret_cast<const float4*>(&bias[cb * 8]);
            const float4 b1 = *reinterpret_cast<const float4*>(&bias[cb * 8 + 4]);
            float4 o0, o1;
            o0.x = fmaxf(acc8[0] * inv + b0.x, 0.f);
            o0.y = fmaxf(acc8[1] * inv + b0.y, 0.f);
            o0.z = fmaxf(acc8[2] * inv + b0.z, 0.f);
            o0.w = fmaxf(acc8[3] * inv + b0.w, 0.f);
            o1.x = fmaxf(acc8[4] * inv + b1.x, 0.f);
            o1.y = fmaxf(acc8[5] * inv + b1.y, 0.f);
            o1.z = fmaxf(acc8[6] * inv + b1.z, 0.f);
            o1.w = fmaxf(acc8[7] * inv + b1.w, 0.f);
            float* op = &out[(size_t)node * OUT_F + cb * 8];
            *reinterpret_cast<float4*>(op) = o0;
            *reinterpret_cast<float4*>(op + 4) = o1;
        }
    }
}

extern "C" void kernel_launch(void* const* d_in, const int* in_sizes, int n_in,
                              void* d_out, int out_size, void* d_ws, size_t ws_size,
                              hipStream_t stream) {
    const float* x       = (const float*)d_in[0];
    const int*   ei      = (const int*)d_in[1];
    const float* W       = (const float*)d_in[2];
    const float* att_src = (const float*)d_in[3];
    const float* att_dst = (const float*)d_in[4];
    const float* bias    = (const float*)d_in[5];
    float* out = (float*)d_out;

    char* wsp = (char*)d_ws;
    unsigned short* h = (unsigned short*)wsp;
    wsp += (size_t)N_NODES * OUT_F * sizeof(unsigned short);
    float* a_src = (float*)wsp; wsp += (size_t)N_NODES * sizeof(float);
    float* a_dst = (float*)wsp; wsp += (size_t)N_NODES * sizeof(float);
    int*   gcnt  = (int*)wsp;   wsp += (size_t)NPART * sizeof(int);
    wsp = (char*)(((size_t)wsp + 15) & ~(size_t)15);
    unsigned short* wa = (unsigned short*)wsp; wsp += IN_F * sizeof(unsigned short);
    unsigned short* wd = (unsigned short*)wsp; wsp += IN_F * sizeof(unsigned short);
    wsp = (char*)(((size_t)wsp + 15) & ~(size_t)15);
    unsigned* glist = (unsigned*)wsp;
    wsp += (size_t)NPART * PADCAP * sizeof(unsigned);

    hipLaunchKernelGGL(k_prep, dim3(1), dim3(256), 0, stream,
                       W, att_src, att_dst, wa, wd, gcnt);
    hipLaunchKernelGGL(k_fused, dim3(GB + NCHUNK), dim3(256), 0, stream,
                       x, W, wa, wd, ei, h, a_src, a_dst, gcnt, glist);
    hipLaunchKernelGGL(k_csr_node, dim3(NPART), dim3(1024), 0, stream,
                       gcnt, glist, a_src, a_dst, h, bias, out);
}